// Round 6
// baseline (485.907 us; speedup 1.0000x reference)
//
#include <hip/hip_runtime.h>
#include <hip/hip_bf16.h>

typedef __attribute__((ext_vector_type(8))) short short8_t;
typedef __attribute__((ext_vector_type(4))) float float4v;

__device__ __forceinline__ float lrelu(float x) { return x > 0.f ? x : 0.2f * x; }
__device__ __forceinline__ float blo(unsigned u) { return __uint_as_float(u << 16); }
__device__ __forceinline__ float bhi(unsigned u) { return __uint_as_float(u & 0xffff0000u); }

__device__ __forceinline__ short8_t mk8(unsigned a, unsigned b, unsigned c, unsigned d) {
    union { unsigned u[4]; short8_t s; } x;
    x.u[0] = a; x.u[1] = b; x.u[2] = c; x.u[3] = d;
    return x.s;
}

// split 8 fp32 (two float4) into bf16 hi / lo fragments (packed 2-per-dword)
__device__ __forceinline__ void split8(const float4& f0, const float4& f1,
                                       short8_t& hi8, short8_t& lo8) {
    float xs[8] = {f0.x, f0.y, f0.z, f0.w, f1.x, f1.y, f1.z, f1.w};
    unsigned h[4], l4[4];
#pragma unroll
    for (int p = 0; p < 4; ++p) {
        unsigned b0 = __float_as_uint(xs[2 * p]);
        unsigned b1 = __float_as_uint(xs[2 * p + 1]);
        unsigned h0b = b0 & 0xffff0000u, h1b = b1 & 0xffff0000u;
        h[p] = (h0b >> 16) | h1b;
        float l0 = xs[2 * p] - __uint_as_float(h0b);
        float l1 = xs[2 * p + 1] - __uint_as_float(h1b);
        l4[p] = (__float_as_uint(l0) >> 16) | (__float_as_uint(l1) & 0xffff0000u);
    }
    hi8 = mk8(h[0], h[1], h[2], h[3]);
    lo8 = mk8(l4[0], l4[1], l4[2], l4[3]);
}

// ---------------------------------------------------------------------------
// hist + prep merged.  Block 0: prep (w_er, Wn, fb, W bf16 split).
// Blocks 1..: degree histogram into PADDED counters (1 counter / 64B line)
// to avoid same-line atomic serialization.
// ---------------------------------------------------------------------------
__global__ void k_histprep(const int* __restrict__ dst, int* __restrict__ deg_p,
                           const float* __restrict__ Wdst,
                           const float* __restrict__ attn_r,
                           const float* __restrict__ fcW,
                           const float* __restrict__ fcb,
                           const float* __restrict__ Wsrc,
                           float* __restrict__ w_er, float* __restrict__ Wn,
                           float* __restrict__ fb,
                           unsigned short* __restrict__ Wb_hi,
                           unsigned short* __restrict__ Wb_lo, int E) {
    int t = threadIdx.x;
    if (blockIdx.x == 0) {
#pragma unroll
        for (int j = 0; j < 32; ++j) {
            int i = t + j * 256;
            float x = Wsrc[i];
            unsigned hb = __float_as_uint(x) & 0xffff0000u;
            float lf = x - __uint_as_float(hb);
            Wb_hi[i] = (unsigned short)(hb >> 16);
            Wb_lo[i] = (unsigned short)(__float_as_uint(lf) >> 16);
        }
        {
            int h0 = t >> 7, i = t & 127;
            float s = 0.f;
            for (int d = 0; d < 32; ++d)
                s += attn_r[h0 * 32 + d] * Wdst[(size_t)(h0 * 32 + d) * 128 + i];
            w_er[t] = s;
        }
        if (t < 16) {
            int oh = t >> 2, k = t & 3;
            float w[4], m = -1e30f;
            for (int j = 0; j < 4; ++j) {
                w[j] = fcW[oh * 4 + j];
                m = fmaxf(m, w[j]);
            }
            float s = 0.f;
            for (int j = 0; j < 4; ++j) s += __expf(w[j] - m);
            Wn[t] = __expf(w[k] - m) / s;
        }
        if (t < 4) fb[t] = fcb[t];
        return;
    }
    int e = (blockIdx.x - 1) * 256 + t;
    if (e < E) atomicAdd(&deg_p[(size_t)dst[e] * 16], 1);
}

// ---------------------------------------------------------------------------
// Slab alloc from padded deg; writes odrec[d].xy = {off, deg} (one 16B
// record per dst; .zw = er filled later by featA) and padded cursor.
// ---------------------------------------------------------------------------
__global__ void k_alloc(const int* __restrict__ deg_p, int* __restrict__ odrec,
                        int* __restrict__ cursor_p, int* __restrict__ counter,
                        int N) {
    int d = blockIdx.x * blockDim.x + threadIdx.x;
    int lane = threadIdx.x & 63;
    int v = (d < N) ? deg_p[(size_t)d * 16] : 0;
    int inc = v;
#pragma unroll
    for (int m = 1; m < 64; m <<= 1) {
        int u = __shfl_up(inc, m, 64);
        if (lane >= m) inc += u;
    }
    int excl = inc - v;
    int base = 0;
    if (lane == 63) base = atomicAdd(counter, inc);
    base = __shfl(base, 63, 64);
    if (d < N) {
        int off = base + excl;
        reinterpret_cast<int2*>(odrec)[(size_t)d * 2] = make_int2(off, v);
        cursor_p[(size_t)d * 16] = off;
    }
}

// ---------------------------------------------------------------------------
// Phase A (MFMA): feat projection (bf16 out) + el  AND  er tiles, with the
// edge SCATTER fused in (padded cursor, nt stores).
//   tile < ntiles        : feat M-tile over hier1 rows -> featb + el
//   ntiles <= t < ntilesT: er tile over hier0 nodes    -> odrec[].zw
// ---------------------------------------------------------------------------
__global__ __launch_bounds__(256) void k_featA(
        const float* __restrict__ hier1, const float* __restrict__ hier0,
        const unsigned short* __restrict__ Wb_hi,
        const unsigned short* __restrict__ Wb_lo,
        const float* __restrict__ attn_l, const float* __restrict__ w_er,
        const int* __restrict__ srcIdx, const int* __restrict__ dstIdx,
        int* __restrict__ cursor_p, int* __restrict__ ssrc,
        unsigned short* __restrict__ featb, float* __restrict__ el,
        float* __restrict__ erbuf,   // = (float*)odrec; er at [d*4+2+h0]
        int nrows, int Ndst, int E, int ntiles, int ntilesT) {
    int t = threadIdx.x;
    int w = t >> 6, lane = t & 63;
    int lr = lane & 15;   // A row / B col / D col
    int lg = lane >> 4;   // k sub-chunk group / D row group

    // ---- edge indices FIRST (so the atomic below waits only on these) ----
    int e = blockIdx.x * 256 + t;
    bool hasE = e < E;
    int es = 0, ed = 0;
    if (hasE) { es = srcIdx[e]; ed = dstIdx[e]; }

    int tile = blockIdx.x * 4 + w;
    bool isFeat = tile < ntiles;
    bool isEr = (tile >= ntiles) && (tile < ntilesT);

    // ---- issue A loads (16 rows x K=128 fp32) ----
    float4 areg[8];
    if (isFeat || isEr) {
        const float* hrow;
        if (isFeat) {
            int row_l = tile * 16 + lr;
            if (row_l >= nrows) row_l = nrows - 1;
            hrow = hier1 + (size_t)row_l * 128 + lg * 8;
        } else {
            int node = (tile - ntiles) * 16 + lr;
            if (node >= Ndst) node = Ndst - 1;
            hrow = hier0 + (size_t)node * 128 + lg * 8;
        }
#pragma unroll
        for (int kc = 0; kc < 4; ++kc) {
            areg[2 * kc]     = *reinterpret_cast<const float4*>(hrow + kc * 32);
            areg[2 * kc + 1] = *reinterpret_cast<const float4*>(hrow + kc * 32 + 4);
        }
    }

    // ---- fused scatter (atomic latency hides under A loads / MFMA) ----
    if (hasE) {
        int pos = atomicAdd(&cursor_p[(size_t)ed * 16], 1);
        __builtin_nontemporal_store(es, &ssrc[pos]);
    }

    if (!(isFeat || isEr)) return;

    // ---- convert A to bf16 hi/lo fragments ----
    short8_t a_hi[4], a_lo[4];
#pragma unroll
    for (int kc = 0; kc < 4; ++kc)
        split8(areg[2 * kc], areg[2 * kc + 1], a_hi[kc], a_lo[kc]);

    if (isFeat) {
        int m0 = tile * 16;
        float4v acc[4];
#pragma unroll
        for (int n = 0; n < 4; ++n) acc[n] = (float4v){0.f, 0.f, 0.f, 0.f};
#pragma unroll
        for (int n = 0; n < 4; ++n) {
            const unsigned short* bh = Wb_hi + (size_t)(n * 16 + lr) * 128 + lg * 8;
            const unsigned short* bl = Wb_lo + (size_t)(n * 16 + lr) * 128 + lg * 8;
#pragma unroll
            for (int kc = 0; kc < 4; ++kc) {
                short8_t Bh = *reinterpret_cast<const short8_t*>(bh + kc * 32);
                short8_t Bl = *reinterpret_cast<const short8_t*>(bl + kc * 32);
                acc[n] = __builtin_amdgcn_mfma_f32_16x16x32_bf16(a_lo[kc], Bh, acc[n], 0, 0, 0);
                acc[n] = __builtin_amdgcn_mfma_f32_16x16x32_bf16(a_hi[kc], Bl, acc[n], 0, 0, 0);
                acc[n] = __builtin_amdgcn_mfma_f32_16x16x32_bf16(a_hi[kc], Bh, acc[n], 0, 0, 0);
            }
        }

        // ---- epilogue: featb store (bf16, nt) + el partials ----
        float pe0[4] = {0.f, 0.f, 0.f, 0.f};
        float pe1[4] = {0.f, 0.f, 0.f, 0.f};
#pragma unroll
        for (int n = 0; n < 4; ++n) {
            float al = attn_l[n * 16 + lr];
#pragma unroll
            for (int r = 0; r < 4; ++r) {
                int row = m0 + lg * 4 + r;
                float v = acc[n][r];
                if (row < nrows) {
                    __hip_bfloat16 bv = __float2bfloat16(v);
                    unsigned short us = *reinterpret_cast<unsigned short*>(&bv);
                    __builtin_nontemporal_store(us,
                        &featb[((size_t)(row >> 1)) * 128 + (row & 1) * 64 + n * 16 + lr]);
                }
                if (n < 2) pe0[r] += v * al; else pe1[r] += v * al;
            }
        }
#pragma unroll
        for (int m = 1; m <= 8; m <<= 1) {
#pragma unroll
            for (int r = 0; r < 4; ++r) {
                pe0[r] += __shfl_xor(pe0[r], m, 64);
                pe1[r] += __shfl_xor(pe1[r], m, 64);
            }
        }
        if (lr < 2) {
#pragma unroll
            for (int r = 0; r < 4; ++r) {
                int row = m0 + lg * 4 + r;
                float ev = lr ? pe1[r] : pe0[r];
                if (row < nrows) el[row * 2 + lr] = ev;
            }
        }
    } else {
        // ---- er tile: [16 x 128] * [128 x 2] with per-K-chunk B frags ----
        int m0 = (tile - ntiles) * 16;
        short8_t Bh[4], Bl[4];
#pragma unroll
        for (int kc = 0; kc < 4; ++kc) {
            Bh[kc] = mk8(0, 0, 0, 0);
            Bl[kc] = mk8(0, 0, 0, 0);
        }
        if (lr < 2) {
#pragma unroll
            for (int kc = 0; kc < 4; ++kc) {
                float4 f0 = *reinterpret_cast<const float4*>(w_er + lr * 128 + kc * 32 + lg * 8);
                float4 f1 = *reinterpret_cast<const float4*>(w_er + lr * 128 + kc * 32 + lg * 8 + 4);
                split8(f0, f1, Bh[kc], Bl[kc]);
            }
        }
        float4v acc = (float4v){0.f, 0.f, 0.f, 0.f};
#pragma unroll
        for (int kc = 0; kc < 4; ++kc) {
            acc = __builtin_amdgcn_mfma_f32_16x16x32_bf16(a_lo[kc], Bh[kc], acc, 0, 0, 0);
            acc = __builtin_amdgcn_mfma_f32_16x16x32_bf16(a_hi[kc], Bl[kc], acc, 0, 0, 0);
            acc = __builtin_amdgcn_mfma_f32_16x16x32_bf16(a_hi[kc], Bh[kc], acc, 0, 0, 0);
        }
        if (lr < 2) {
#pragma unroll
            for (int r = 0; r < 4; ++r) {
                int nn = m0 + lg * 4 + r;
                if (nn < Ndst) erbuf[(size_t)nn * 4 + 2 + lr] = acc[r];
            }
        }
    }
}

// ---------------------------------------------------------------------------
// Gather + fused epilogue.  ONE WAVE per dst, EIGHT edges per iteration.
//   Per-dst state (off, deg, er0, er1) = ONE 16B record -> 1 serial RT.
//   fA1 (2nd 16B of the lane's 32B chunk) is loaded JIT: same 64B line as
//   fA0 -> L2 hit, saves 16 VGPRs of prefetch state.
//   __launch_bounds__(256, 8): target <=64 VGPR -> 8 waves/SIMD.
// ---------------------------------------------------------------------------
__global__ __launch_bounds__(256, 8) void k_gather(
        const int* __restrict__ ssrc, const int4* __restrict__ odrec,
        const float* __restrict__ el,
        const uint4* __restrict__ feat4,
        const float* __restrict__ bias,
        const float* __restrict__ Wn, const float* __restrict__ fb,
        float* __restrict__ out, int Ndst, int E) {
    __shared__ float g[4][128];
    int t = threadIdx.x;
    int wv = t >> 6, lane = t & 63;
    int d = blockIdx.x * 4 + wv;
    bool valid = d < Ndst;

    int q = lane >> 3;          // edge slot within group of 8
    int c = lane & 7;           // 32B chunk: bf16 cols 16c..16c+15
    int k = c >> 1;             // h1*2 + h0 for these cols

    int4 rec = valid ? odrec[d] : make_int4(0, 0, 0, 0);
    int start = rec.x, n = rec.y;
    float erk = (k & 1) ? __int_as_float(rec.w) : __int_as_float(rec.z);

    float a[16];
#pragma unroll
    for (int j = 0; j < 16; ++j) a[j] = 0.f;
    float den = 0.f;

    int base = start + q;
    int sCur = ssrc[base < E ? base : 0];
    int sNext = ssrc[(base + 8) < E ? (base + 8) : 0];
    uint4 fA0 = feat4[(size_t)sCur * 16 + 2 * c];
    float eA = el[sCur * 4 + k];

    for (int i = 0; i < n; i += 8) {
        uint4 fA1 = feat4[(size_t)sCur * 16 + 2 * c + 1];  // same line as fA0
        uint4 fB0 = feat4[(size_t)sNext * 16 + 2 * c];     // next group
        float eB = el[sNext * 4 + k];
        int nx = base + i + 16;
        int sFut = ssrc[nx < E ? nx : 0];

        bool ve = (i + q) < n;
        float ee = ve ? __expf(lrelu(eA + erk)) : 0.f;
        den += ee;
        a[0]  = fmaf(ee, blo(fA0.x), a[0]);
        a[1]  = fmaf(ee, bhi(fA0.x), a[1]);
        a[2]  = fmaf(ee, blo(fA0.y), a[2]);
        a[3]  = fmaf(ee, bhi(fA0.y), a[3]);
        a[4]  = fmaf(ee, blo(fA0.z), a[4]);
        a[5]  = fmaf(ee, bhi(fA0.z), a[5]);
        a[6]  = fmaf(ee, blo(fA0.w), a[6]);
        a[7]  = fmaf(ee, bhi(fA0.w), a[7]);
        a[8]  = fmaf(ee, blo(fA1.x), a[8]);
        a[9]  = fmaf(ee, bhi(fA1.x), a[9]);
        a[10] = fmaf(ee, blo(fA1.y), a[10]);
        a[11] = fmaf(ee, bhi(fA1.y), a[11]);
        a[12] = fmaf(ee, blo(fA1.z), a[12]);
        a[13] = fmaf(ee, bhi(fA1.z), a[13]);
        a[14] = fmaf(ee, blo(fA1.w), a[14]);
        a[15] = fmaf(ee, bhi(fA1.w), a[15]);

        sCur = sNext; sNext = sFut; fA0 = fB0; eA = eB;
    }

    // merge the 8 edge-slots: lanes {c, c+8, ..., c+56}
#pragma unroll
    for (int m = 8; m <= 32; m <<= 1) {
        den += __shfl_xor(den, m, 64);
#pragma unroll
        for (int j = 0; j < 16; ++j) a[j] += __shfl_xor(a[j], m, 64);
    }

    float inv = den > 0.f ? 1.f / den : 0.f;
    if (q == 0) {                         // lanes 0..7 hold full sums
        int h0 = k & 1;
        int db = (c & 1) * 16;
#pragma unroll
        for (int j = 0; j < 16; ++j)
            g[wv][c * 16 + j] = a[j] * inv + bias[h0 * 32 + db + j];
    }
    __syncthreads();

    if (valid) {
        int dd = (lane & 15) * 2;
        int oh = lane >> 4;
        float r0 = fb[oh], r1 = r0;
#pragma unroll
        for (int kk = 0; kk < 4; ++kk) {
            float wgt = Wn[oh * 4 + kk];
            r0 = fmaf(g[wv][kk * 32 + dd], wgt, r0);
            r1 = fmaf(g[wv][kk * 32 + dd + 1], wgt, r1);
        }
        *reinterpret_cast<float2*>(out + (size_t)d * 128 + lane * 2) =
            make_float2(r0, r1);
    }
}

// ---------------------------------------------------------------------------
extern "C" void kernel_launch(void* const* d_in, const int* in_sizes, int n_in,
                              void* d_out, int out_size, void* d_ws, size_t ws_size,
                              hipStream_t stream) {
    (void)n_in; (void)out_size; (void)ws_size;
    const float* hier1  = (const float*)d_in[0];
    const float* hier0  = (const float*)d_in[1];
    const int*   srcIdx = (const int*)d_in[2];
    const int*   dstIdx = (const int*)d_in[3];
    const float* Wsrc   = (const float*)d_in[4];
    const float* Wdst   = (const float*)d_in[5];
    const float* attn_l = (const float*)d_in[6];
    const float* attn_r = (const float*)d_in[7];
    const float* bias   = (const float*)d_in[8];
    const float* fcW    = (const float*)d_in[9];
    const float* fcb    = (const float*)d_in[10];
    float* out = (float*)d_out;

    const int Nsrc  = in_sizes[0] / 256;  // N_SRC (H1=2, IN1=128)
    const int Ndst  = in_sizes[1] / 128;  // N_DST (IN0=128)
    const int E     = in_sizes[2];
    const int nrows = Nsrc * 2;           // N_SRC * H1
    const int ntiles  = (nrows + 15) / 16;
    const int ntilesE = (Ndst + 15) / 16;
    const int ntilesT = ntiles + ntilesE;

    // ws layout (all sub-arrays 16B-aligned by construction)
    unsigned short* featb = (unsigned short*)d_ws;              // Nsrc*128 bf16
    unsigned short* Wb_hi = featb + (size_t)Nsrc * 128;         // 8192
    unsigned short* Wb_lo = Wb_hi + 8192;                       // 8192
    float* el   = (float*)(Wb_lo + 8192);                       // nrows*2
    float* w_er = el + (size_t)nrows * 2;                       // 256
    float* Wn   = w_er + 256;                                   // 16
    float* fb   = Wn + 16;                                      // 4 (+12 pad)
    int*  deg_p    = (int*)(fb + 16);                           // Ndst*16 (padded)
    int*  cursor_p = deg_p + (size_t)Ndst * 16;                 // Ndst*16 (padded)
    int*  odrec    = cursor_p + (size_t)Ndst * 16;              // Ndst*4 (int4)
    int*  counter  = odrec + (size_t)Ndst * 4;                  // 1 (+3 pad)
    int*  ssrc     = counter + 4;                               // E

    hipMemsetAsync(deg_p, 0, (size_t)Ndst * 16 * sizeof(int), stream);
    hipMemsetAsync(counter, 0, sizeof(int), stream);

    int blocksH = (E + 255) / 256 + 1;
    k_histprep<<<blocksH, 256, 0, stream>>>(dstIdx, deg_p, Wdst, attn_r,
                                            fcW, fcb, Wsrc,
                                            w_er, Wn, fb, Wb_hi, Wb_lo, E);

    k_alloc<<<(Ndst + 255) / 256, 256, 0, stream>>>(deg_p, odrec, cursor_p,
                                                    counter, Ndst);

    int blocksA = (ntilesT + 3) / 4;
    int blocksE2 = (E + 255) / 256;
    if (blocksE2 > blocksA) blocksA = blocksE2;
    k_featA<<<blocksA, 256, 0, stream>>>(hier1, hier0, Wb_hi, Wb_lo,
                                         attn_l, w_er,
                                         srcIdx, dstIdx, cursor_p, ssrc,
                                         featb, el, (float*)odrec,
                                         nrows, Ndst, E, ntiles, ntilesT);

    k_gather<<<(Ndst + 3) / 4, 256, 0, stream>>>(ssrc, (const int4*)odrec, el,
                                                 (const uint4*)featb,
                                                 bias, Wn, fb, out, Ndst, E);
}